// Round 2
// baseline (431.475 us; speedup 1.0000x reference)
//
#include <hip/hip_runtime.h>
#include <hip/hip_bf16.h>

typedef float f32x4 __attribute__((ext_vector_type(4)));
typedef short short8 __attribute__((ext_vector_type(8)));

#define BATCH 8
#define CH    128
#define HWN   50176
#define PN    128
#define KSPLIT 64
#define KWIN  784          // HWN / KSPLIT
#define BK    32           // fp32 columns staged per stage
#define NFULL 24           // full BK stages; tail = 16 cols
#define TAILOFF (NFULL*BK) // 768

__device__ __forceinline__ ushort f2bf_rn(float f){
  uint u = __float_as_uint(f);
  u += 0x7FFFu + ((u >> 16) & 1u);       // round-to-nearest-even
  return (ushort)(u >> 16);
}
__device__ __forceinline__ float bf2f(ushort h){
  return __uint_as_float(((uint)h) << 16);
}

// mask values are exactly 0.0f / 1.0f -> truncation is exact
__device__ __forceinline__ short8 cvt8_trunc(f32x4 a, f32x4 b){
  union{ short8 v; ushort u[8]; } r;
  r.u[0]=(ushort)(__float_as_uint(a.x)>>16); r.u[1]=(ushort)(__float_as_uint(a.y)>>16);
  r.u[2]=(ushort)(__float_as_uint(a.z)>>16); r.u[3]=(ushort)(__float_as_uint(a.w)>>16);
  r.u[4]=(ushort)(__float_as_uint(b.x)>>16); r.u[5]=(ushort)(__float_as_uint(b.y)>>16);
  r.u[6]=(ushort)(__float_as_uint(b.z)>>16); r.u[7]=(ushort)(__float_as_uint(b.w)>>16);
  return r.v;
}

__device__ __forceinline__ void cvt8_hilo(f32x4 a, f32x4 b, short8& h8, short8& l8){
  union{ short8 v; ushort u[8]; } h, l;
  float f[8] = {a.x,a.y,a.z,a.w,b.x,b.y,b.z,b.w};
  #pragma unroll
  for(int j=0;j<8;++j){
    ushort hh = f2bf_rn(f[j]);
    h.u[j] = hh;
    l.u[j] = f2bf_rn(f[j] - bf2f(hh));
  }
  h8 = h.v; l8 = l.v;
}

__device__ __forceinline__ void gload16(const float* g, float* l){
  __builtin_amdgcn_global_load_lds(
      (const __attribute__((address_space(1))) void*)g,
      (__attribute__((address_space(3))) void*)l, 16, 0, 0);
}

// swizzled fp32 LDS addressing: element (row, kf) at float index
//   row*32 + (((kf>>2) ^ (row&7)) << 2) + (kf&3)
__device__ __forceinline__ f32x4 lds_read4(const float* base, int r, int slot){
  return *(const f32x4*)(base + r*32 + ((slot ^ (r&7)) << 2));
}
__device__ __forceinline__ void lds_write4(float* base, int r, int slot, f32x4 v){
  *(f32x4*)(base + r*32 + ((slot ^ (r&7)) << 2)) = v;
}

// ---------------------------------------------------------------------------
// block = (batch b, k-split s): 128x128 partial over k-window [s*784,(s+1)*784)
// fp32 staged to LDS via global_load_lds (pre-swizzled source); bf16 hi/lo
// split conversion at consume; fp32 MFMA accumulate.
// ---------------------------------------------------------------------------
template<int EPI>
__global__ __launch_bounds__(256, 2)
void raggr_kernel(const float* __restrict__ X, const float* __restrict__ Mk,
                  float* __restrict__ OUT, float* __restrict__ PART){
  __shared__ float lds[2][2][4096];   // [buf][arr: 0=X 1=M][128 rows][32 cols] swizzled

  const int tid  = threadIdx.x;
  const int b    = blockIdx.x >> 6;
  const int s    = blockIdx.x & 63;
  const int lane = tid & 63;
  const int w    = tid >> 6;
  const int wrow = (w >> 1) * 64;
  const int wcol = (w & 1) * 64;

  const size_t base = (size_t)b * CH * HWN + (size_t)s * KWIN;
  const f32x4 z4 = {0.f,0.f,0.f,0.f};

  f32x4 acc[4][4];
  #pragma unroll
  for(int m=0;m<4;++m)
    #pragma unroll
    for(int n=0;n<4;++n) acc[m][n] = z4;

  // --- staging source pointers (inverse-swizzled so linear LDS dest == swizzled tile)
  // chunk c = w*4+i covers LDS bytes [c*1024, c*1024+1024): lane l writes c*1024+l*16
  //   row = c*8 + (l>>3), 16B-slot-in-LDS = l&7  ->  k-slot kq = (l&7) ^ (l>>3)
  const int lrow = lane >> 3;
  const int kq   = (lane & 7) ^ lrow;
  const float* pX[4]; const float* pM[4];
  #pragma unroll
  for(int i=0;i<4;++i){
    int r = w*32 + i*8 + lrow;
    pX[i] = X  + base + (size_t)r * HWN + kq*4;
    pM[i] = Mk + base + (size_t)r * HWN + kq*4;
  }

  #define STAGE(tt, buf) {                                                    \
    _Pragma("unroll")                                                         \
    for(int i=0;i<4;++i){                                                     \
      gload16(pX[i] + (tt)*BK, &lds[buf][0][(w*4+i)*256]);                    \
      gload16(pM[i] + (tt)*BK, &lds[buf][1][(w*4+i)*256]);                    \
    } }

  #define COMPUTE(buf) {                                                      \
    const float* Xb = lds[buf][0];                                            \
    const float* Mb = lds[buf][1];                                            \
    const int l15 = lane & 15;                                                \
    const int s0  = (lane >> 4) * 2;                                          \
    short8 bf[4], ah[4], al[4];                                               \
    _Pragma("unroll")                                                         \
    for(int n=0;n<4;++n){                                                     \
      int r = wcol + n*16 + l15;                                              \
      bf[n] = cvt8_trunc(lds_read4(Mb, r, s0), lds_read4(Mb, r, s0+1));       \
    }                                                                         \
    _Pragma("unroll")                                                         \
    for(int m=0;m<4;++m){                                                     \
      int r = wrow + m*16 + l15;                                              \
      cvt8_hilo(lds_read4(Xb, r, s0), lds_read4(Xb, r, s0+1), ah[m], al[m]);  \
    }                                                                         \
    _Pragma("unroll")                                                         \
    for(int m=0;m<4;++m)                                                      \
      _Pragma("unroll")                                                       \
      for(int n=0;n<4;++n){                                                   \
        acc[m][n] = __builtin_amdgcn_mfma_f32_16x16x32_bf16(ah[m], bf[n], acc[m][n], 0,0,0); \
        acc[m][n] = __builtin_amdgcn_mfma_f32_16x16x32_bf16(al[m], bf[n], acc[m][n], 0,0,0); \
      }                                                                       \
  }

  STAGE(0, 0);
  __syncthreads();

  #pragma unroll 1
  for(int t=0; t<NFULL; ++t){
    if(t+1 < NFULL) STAGE(t+1, (t+1)&1);   // in flight across compute
    COMPUTE(t&1);
    __syncthreads();                        // drains prefetch + lds reads
  }

  // --- tail stage: 16 valid k-cols, reg-staged with explicit zero upper half
  {
    int r    = tid >> 1;           // 0..127
    int half = tid & 1;            // 0..1
    size_t g = base + (size_t)r * HWN + TAILOFF + half*8;
    f32x4 x0 = *(const f32x4*)(X + g),  x1 = *(const f32x4*)(X + g + 4);
    f32x4 m0 = *(const f32x4*)(Mk + g), m1 = *(const f32x4*)(Mk + g + 4);
    float* Xb = lds[0][0]; float* Mb = lds[0][1];
    lds_write4(Xb, r, half*2,   x0); lds_write4(Xb, r, half*2+1, x1);
    lds_write4(Xb, r, 4+half*2, z4); lds_write4(Xb, r, 5+half*2, z4);
    lds_write4(Mb, r, half*2,   m0); lds_write4(Mb, r, half*2+1, m1);
    lds_write4(Mb, r, 4+half*2, z4); lds_write4(Mb, r, 5+half*2, z4);
    __syncthreads();
    COMPUTE(0);
  }

  // --- epilogue: C/D layout col=lane&15, row=(lane>>4)*4+j  [m89]
  if(EPI == 0){
    float* p = PART + ((size_t)(b*KSPLIT + s)) * 16384;
    #pragma unroll
    for(int m=0;m<4;++m){
      int row0 = wrow + m*16 + ((lane >> 4) << 2);
      #pragma unroll
      for(int n=0;n<4;++n){
        int col = wcol + n*16 + (lane & 15);
        #pragma unroll
        for(int j=0;j<4;++j) p[(size_t)(row0+j)*128 + col] = acc[m][n][j];
      }
    }
  } else {
    float* o = OUT + (size_t)b * 16384;
    #pragma unroll
    for(int m=0;m<4;++m){
      int row0 = wrow + m*16 + ((lane >> 4) << 2);
      #pragma unroll
      for(int n=0;n<4;++n){
        int col = wcol + n*16 + (lane & 15);
        #pragma unroll
        for(int j=0;j<4;++j) atomicAdd(&o[(size_t)(row0+j)*128 + col], acc[m][n][j]);
      }
    }
  }
  #undef STAGE
  #undef COMPUTE
}

// sum 64 k-split partials -> out.  32768 threads x 1 float4 each.
__global__ void reduce_kernel(const float* __restrict__ PART, float* __restrict__ OUT){
  int idx = blockIdx.x * 256 + threadIdx.x;      // 0 .. 32767
  int b   = idx >> 12;                           // 4096 float4 per batch
  int c4  = idx & 4095;
  const f32x4* p = (const f32x4*)PART;
  f32x4 sum = {0.f,0.f,0.f,0.f};
  size_t base_ = (size_t)b * KSPLIT * 4096 + (size_t)c4;
  #pragma unroll 8
  for(int s2=0; s2<KSPLIT; ++s2) sum += p[base_ + (size_t)s2*4096];
  ((f32x4*)OUT)[idx] = sum;
}

__global__ void zero_kernel(float* __restrict__ OUT){
  int idx = blockIdx.x * 256 + threadIdx.x;
  if(idx < BATCH*CH*PN) OUT[idx] = 0.f;
}

extern "C" void kernel_launch(void* const* d_in, const int* in_sizes, int n_in,
                              void* d_out, int out_size, void* d_ws, size_t ws_size,
                              hipStream_t stream){
  const float* X  = (const float*)d_in[0];
  const float* Mk = (const float*)d_in[1];
  float* O = (float*)d_out;

  const size_t part_bytes = (size_t)BATCH * KSPLIT * CH * PN * sizeof(float); // 33.5 MB
  if(ws_size >= part_bytes && d_ws != nullptr){
    float* part = (float*)d_ws;
    raggr_kernel<0><<<dim3(BATCH*KSPLIT), dim3(256), 0, stream>>>(X, Mk, O, part);
    reduce_kernel<<<dim3(128), dim3(256), 0, stream>>>(part, O);
  } else {
    zero_kernel<<<dim3(512), dim3(256), 0, stream>>>(O);
    raggr_kernel<1><<<dim3(BATCH*KSPLIT), dim3(256), 0, stream>>>(X, Mk, O, nullptr);
  }
}

// Round 3
// 421.727 us; speedup vs baseline: 1.0231x; 1.0231x over previous
//
#include <hip/hip_runtime.h>
#include <hip/hip_bf16.h>

typedef float f32x4 __attribute__((ext_vector_type(4)));
typedef short short8 __attribute__((ext_vector_type(8)));

#define BATCH 8
#define CH    128
#define HWN   50176
#define PN    128
#define KSPLIT 32
#define KWIN  1568         // HWN / KSPLIT
#define BK    32           // fp32 k-columns per stage
#define NST   49           // KWIN / BK, exact — no tail

__device__ __forceinline__ ushort f2bf_rn(float f){
  uint u = __float_as_uint(f);
  u += 0x7FFFu + ((u >> 16) & 1u);
  return (ushort)(u >> 16);
}
__device__ __forceinline__ float bf2f(ushort h){
  return __uint_as_float(((uint)h) << 16);
}

// mask values are exactly 0.0f/1.0f -> truncation exact
__device__ __forceinline__ short8 cvt8_trunc(f32x4 a, f32x4 b){
  union{ short8 v; ushort u[8]; } r;
  r.u[0]=(ushort)(__float_as_uint(a.x)>>16); r.u[1]=(ushort)(__float_as_uint(a.y)>>16);
  r.u[2]=(ushort)(__float_as_uint(a.z)>>16); r.u[3]=(ushort)(__float_as_uint(a.w)>>16);
  r.u[4]=(ushort)(__float_as_uint(b.x)>>16); r.u[5]=(ushort)(__float_as_uint(b.y)>>16);
  r.u[6]=(ushort)(__float_as_uint(b.z)>>16); r.u[7]=(ushort)(__float_as_uint(b.w)>>16);
  return r.v;
}

// hi = truncate-to-bf16 (1 op), lo = round(f - hi): captures next 8 mantissa bits
__device__ __forceinline__ void cvt8_hilo(f32x4 a, f32x4 b, short8& h8, short8& l8){
  union{ short8 v; ushort u[8]; } h, l;
  float f[8] = {a.x,a.y,a.z,a.w,b.x,b.y,b.z,b.w};
  #pragma unroll
  for(int j=0;j<8;++j){
    ushort hh = (ushort)(__float_as_uint(f[j]) >> 16);
    h.u[j] = hh;
    l.u[j] = f2bf_rn(f[j] - bf2f(hh));
  }
  h8 = h.v; l8 = l.v;
}

__device__ __forceinline__ void gload16(const float* g, float* l){
  __builtin_amdgcn_global_load_lds(
      (const __attribute__((address_space(1))) void*)g,
      (__attribute__((address_space(3))) void*)l, 16, 0, 0);
}

// swizzled fp32 LDS tile [128][32]: element (r, k) at float idx
//   r*32 + (((k>>2) ^ (r&7)) << 2) + (k&3)
__device__ __forceinline__ f32x4 lds_read4(const float* base, int r, int slot){
  return *(const f32x4*)(base + r*32 + ((slot ^ (r&7)) << 2));
}

// ---------------------------------------------------------------------------
// 256 blocks = (b, s) with s in [0,32): 128x128 partial over k-window of 1568.
// 512 threads / 8 waves (2 row x 4 col, wave tile 64x32).
// 4-deep LDS ring staged via global_load_lds; counted vmcnt (never 0 in loop).
// ---------------------------------------------------------------------------
template<int EPI>
__global__ __launch_bounds__(512, 1)
void raggr_kernel(const float* __restrict__ X, const float* __restrict__ Mk,
                  float* __restrict__ OUT, float* __restrict__ PART){
  __shared__ float lds[4 * 8192];   // 4 bufs x (X[128][32] | M[128][32]) = 128 KB

  const int tid  = threadIdx.x;
  const int b    = blockIdx.x >> 5;
  const int s    = blockIdx.x & 31;
  const int lane = tid & 63;
  const int w    = tid >> 6;          // 0..7
  const int wrow = (w >> 2) * 64;     // output row base (2 groups)
  const int wcol = (w & 3) * 32;      // output col base (4 groups)

  const size_t base = (size_t)b * CH * HWN + (size_t)s * KWIN;
  const f32x4 z4 = {0.f,0.f,0.f,0.f};

  f32x4 acc[4][2];
  #pragma unroll
  for(int m=0;m<4;++m){ acc[m][0]=z4; acc[m][1]=z4; }

  // --- staging assignment: wave w<4 stages X rows (w&3)*32..+31, w>=4 same for M.
  // chunk i covers rows +i*8..+i*8+7; lane l -> row +(l>>3), 16B slot (l&7).
  // inverse-swizzle the GLOBAL k-quarter so linear LDS dest == swizzled tile.
  const int lrow = lane >> 3;
  const int kq   = (lane & 7) ^ lrow;
  const float* SRC = (w >= 4) ? Mk : X;
  const float* ps[4];
  float* ld0[4];
  #pragma unroll
  for(int i=0;i<4;++i){
    int r = (w & 3)*32 + i*8 + lrow;
    ps[i]  = SRC + base + (size_t)r * HWN + kq*4;
    ld0[i] = lds + ((w >= 4) ? 4096 : 0) + ((w & 3)*32 + i*8)*32;
  }

  #define STAGE(tt) {                                                         \
    float* dst = ld0[0] + ((tt) & 3) * 8192;                                  \
    const size_t go = (size_t)(tt) * BK;                                      \
    gload16(ps[0] + go, dst);                                                 \
    gload16(ps[1] + go, ld0[1] + ((tt) & 3) * 8192);                          \
    gload16(ps[2] + go, ld0[2] + ((tt) & 3) * 8192);                          \
    gload16(ps[3] + go, ld0[3] + ((tt) & 3) * 8192);                          \
  }

  #define COMPUTE(tt) {                                                       \
    const float* Xb = lds + ((tt) & 3) * 8192;                                \
    const float* Mb = Xb + 4096;                                              \
    const int l15 = lane & 15;                                                \
    const int s0  = (lane >> 4) * 2;                                          \
    short8 bf[2], ah[4], al[4];                                               \
    _Pragma("unroll")                                                         \
    for(int n=0;n<2;++n){                                                     \
      int r = wcol + n*16 + l15;                                              \
      bf[n] = cvt8_trunc(lds_read4(Mb, r, s0), lds_read4(Mb, r, s0+1));       \
    }                                                                         \
    _Pragma("unroll")                                                         \
    for(int m=0;m<4;++m){                                                     \
      int r = wrow + m*16 + l15;                                              \
      cvt8_hilo(lds_read4(Xb, r, s0), lds_read4(Xb, r, s0+1), ah[m], al[m]);  \
    }                                                                         \
    _Pragma("unroll")                                                         \
    for(int m=0;m<4;++m)                                                      \
      _Pragma("unroll")                                                       \
      for(int n=0;n<2;++n){                                                   \
        acc[m][n] = __builtin_amdgcn_mfma_f32_16x16x32_bf16(ah[m], bf[n], acc[m][n], 0,0,0); \
        acc[m][n] = __builtin_amdgcn_mfma_f32_16x16x32_bf16(al[m], bf[n], acc[m][n], 0,0,0); \
      }                                                                       \
  }

  // prologue: fill pipeline 3 deep (12 loads outstanding per wave)
  STAGE(0); STAGE(1); STAGE(2);

  #pragma unroll 1
  for(int t=0; t<NST; ++t){
    // counted drain: wait only for the OLDEST stage; keep 2 stages in flight
    if(t < NST-2)       asm volatile("s_waitcnt vmcnt(8)" ::: "memory");
    else if(t == NST-2) asm volatile("s_waitcnt vmcnt(4)" ::: "memory");
    else                asm volatile("s_waitcnt vmcnt(0)" ::: "memory");
    __builtin_amdgcn_s_barrier();
    if(t+3 < NST) STAGE(t+3);
    COMPUTE(t);
  }

  // epilogue — C/D layout: col = lane&15, row = (lane>>4)*4 + j  [m89]
  if(EPI == 0){
    // PART layout [b][c][s][p] : idx = b*524288 + row*4096 + s*128 + col
    #pragma unroll
    for(int m=0;m<4;++m){
      int row0 = wrow + m*16 + ((lane >> 4) << 2);
      #pragma unroll
      for(int n=0;n<2;++n){
        int col = wcol + n*16 + (lane & 15);
        #pragma unroll
        for(int j=0;j<4;++j)
          PART[(size_t)b*524288 + (size_t)(row0+j)*4096 + s*128 + col] = acc[m][n][j];
      }
    }
  } else {
    float* o = OUT + (size_t)b * 16384;
    #pragma unroll
    for(int m=0;m<4;++m){
      int row0 = wrow + m*16 + ((lane >> 4) << 2);
      #pragma unroll
      for(int n=0;n<2;++n){
        int col = wcol + n*16 + (lane & 15);
        #pragma unroll
        for(int j=0;j<4;++j) atomicAdd(&o[(size_t)(row0+j)*128 + col], acc[m][n][j]);
      }
    }
  }
  #undef STAGE
  #undef COMPUTE
}

// out[b][c][p] = sum_s PART[b][c][s][p] — fully coalesced reads.
__global__ void reduce_kernel(const float* __restrict__ PART, float* __restrict__ OUT){
  int bid = blockIdx.x;                          // 0..511
  int b   = bid >> 6;
  int c   = (bid & 63)*2 + (threadIdx.x >> 7);   // 0..127
  int p   = threadIdx.x & 127;
  size_t base_ = (size_t)b*524288 + (size_t)c*4096 + p;
  float sum = 0.f;
  #pragma unroll 8
  for(int k=0;k<32;++k) sum += PART[base_ + k*128];
  OUT[(size_t)b*16384 + c*128 + p] = sum;
}

__global__ void zero_kernel(float* __restrict__ OUT){
  int idx = blockIdx.x * 256 + threadIdx.x;
  if(idx < BATCH*CH*PN) OUT[idx] = 0.f;
}

extern "C" void kernel_launch(void* const* d_in, const int* in_sizes, int n_in,
                              void* d_out, int out_size, void* d_ws, size_t ws_size,
                              hipStream_t stream){
  const float* X  = (const float*)d_in[0];
  const float* Mk = (const float*)d_in[1];
  float* O = (float*)d_out;

  const size_t part_bytes = (size_t)BATCH * KSPLIT * CH * PN * sizeof(float); // 16.8 MB
  if(ws_size >= part_bytes && d_ws != nullptr){
    float* part = (float*)d_ws;
    raggr_kernel<0><<<dim3(BATCH*KSPLIT), dim3(512), 0, stream>>>(X, Mk, O, part);
    reduce_kernel<<<dim3(512), dim3(256), 0, stream>>>(part, O);
  } else {
    zero_kernel<<<dim3(512), dim3(256), 0, stream>>>(O);
    raggr_kernel<1><<<dim3(BATCH*KSPLIT), dim3(512), 0, stream>>>(X, Mk, O, nullptr);
  }
}

// Round 4
// 411.887 us; speedup vs baseline: 1.0476x; 1.0239x over previous
//
#include <hip/hip_runtime.h>
#include <hip/hip_bf16.h>

typedef float f32x4 __attribute__((ext_vector_type(4)));
typedef short short8 __attribute__((ext_vector_type(8)));

#define BATCH 8
#define CH    128
#define HWN   50176
#define PN    128
#define KSPLIT 32
#define KWIN  1568         // HWN / KSPLIT
#define BK    224          // fp32 k-cols per stage = 7 k-steps of 32 (896 B/row visit)
#define NST   7            // KWIN / BK exact
#define NKS   49           // NST * 7 flat k-steps

__device__ __forceinline__ ushort f2bf_rn(float f){
  uint u = __float_as_uint(f);
  u += 0x7FFFu + ((u >> 16) & 1u);
  return (ushort)(u >> 16);
}
__device__ __forceinline__ float bf2f(ushort h){
  return __uint_as_float(((uint)h) << 16);
}

// mask values are exactly 0.0f/1.0f -> truncation exact
__device__ __forceinline__ short8 cvt8_trunc(f32x4 a, f32x4 b){
  union{ short8 v; ushort u[8]; } r;
  r.u[0]=(ushort)(__float_as_uint(a.x)>>16); r.u[1]=(ushort)(__float_as_uint(a.y)>>16);
  r.u[2]=(ushort)(__float_as_uint(a.z)>>16); r.u[3]=(ushort)(__float_as_uint(a.w)>>16);
  r.u[4]=(ushort)(__float_as_uint(b.x)>>16); r.u[5]=(ushort)(__float_as_uint(b.y)>>16);
  r.u[6]=(ushort)(__float_as_uint(b.z)>>16); r.u[7]=(ushort)(__float_as_uint(b.w)>>16);
  return r.v;
}

// hi = truncate-to-bf16, lo = rn(f - hi)
__device__ __forceinline__ void cvt8_hilo(f32x4 a, f32x4 b, short8& h8, short8& l8){
  union{ short8 v; ushort u[8]; } h, l;
  float f[8] = {a.x,a.y,a.z,a.w,b.x,b.y,b.z,b.w};
  #pragma unroll
  for(int j=0;j<8;++j){
    ushort hh = (ushort)(__float_as_uint(f[j]) >> 16);
    h.u[j] = hh;
    l.u[j] = f2bf_rn(f[j] - bf2f(hh));
  }
  h8 = h.v; l8 = l.v;
}

// ---------------------------------------------------------------------------
// 256 blocks = (b, s): 128x128 partial over k-window of 1568.
// 512 thr / 8 waves; wave w computes c-rows [w*16, w*16+16) x all 128 p.
// X: per-lane register streaming (contiguous 128 B/step per lane, 4-deep ring).
// M: reg-staged -> bf16 -> swizzled LDS [128][pad 512B], double-buffered.
// ---------------------------------------------------------------------------
template<int EPI>
__global__ __launch_bounds__(512, 1)
void raggr_kernel(const float* __restrict__ X, const float* __restrict__ Mk,
                  float* __restrict__ OUT, float* __restrict__ PART){
  __shared__ char smem[2 * 65536];   // 2 bufs x 128 rows x 512 B (bf16, padded)

  const int tid  = threadIdx.x;
  const int b    = blockIdx.x >> 5;
  const int s    = blockIdx.x & 31;
  const int lane = tid & 63;
  const int w    = tid >> 6;          // 0..7
  const int l15  = lane & 15;
  const int hi4  = lane >> 4;         // 0..3

  const size_t base = (size_t)b * CH * HWN + (size_t)s * KWIN;
  const f32x4 z4 = {0.f,0.f,0.f,0.f};

  // X stream: lane reads row (w*16 + l15), k starts at hi4*8 within each k32
  const float* pX = X + base + (size_t)(w*16 + l15) * HWN + hi4*8;

  // M staging: thread -> row mr, 224B-contiguous chunk mc
  const int mr = tid >> 2;            // 0..127
  const int mc = tid & 3;             // 0..3
  const int r7 = mr & 7;
  const float* pM = Mk + base + (size_t)mr * HWN + mc*56;
  char* mwr = smem + mr*512;          // + buf*65536 + swizzled unit*16

  f32x4 acc[8];
  #pragma unroll
  for(int n=0;n<8;++n) acc[n] = z4;

  f32x4 xr[4][2];    // 4-deep rolling k-step window (static indices only)
  f32x4 mreg[14];    // one M stage in flight

  #define ISSUE_X(g) {                                                        \
    xr[(g)&3][0] = *(const f32x4*)(pX + (size_t)(g)*32);                      \
    xr[(g)&3][1] = *(const f32x4*)(pX + (size_t)(g)*32 + 4);                  \
  }
  #define ISSUE_M(t) {                                                        \
    _Pragma("unroll")                                                         \
    for(int i=0;i<14;++i)                                                     \
      mreg[i] = *(const f32x4*)(pM + (size_t)(t)*BK + i*4);                   \
  }
  // convert mreg -> bf16, write to swizzled LDS buf
  #define CVTW_M(buf) {                                                      \
    char* dst = mwr + (buf)*65536;                                            \
    _Pragma("unroll")                                                         \
    for(int i=0;i<7;++i){                                                     \
      short8 v = cvt8_trunc(mreg[2*i], mreg[2*i+1]);                          \
      *(short8*)(dst + (((mc*7 + i) ^ r7) << 4)) = v;                         \
    } }

  // prologue
  ISSUE_M(0);
  ISSUE_X(0); ISSUE_X(1); ISSUE_X(2); ISSUE_X(3);
  CVTW_M(0);
  ISSUE_M(1);
  __syncthreads();

  #pragma unroll
  for(int g=0; g<NKS; ++g){
    const int t  = g / 7;
    const int ks = g % 7;
    const char* Mb = smem + (t & 1) * 65536;

    // B-frags: p = n*16+l15, 16B unit = (ks*4 + hi4) ^ (p&7)
    short8 bf[8];
    #pragma unroll
    for(int n=0;n<8;++n){
      int p = n*16 + l15;
      bf[n] = *(const short8*)(Mb + p*512 + (((ks*4 + hi4) ^ (p & 7)) << 4));
    }
    // A-frags from streamed regs
    short8 ah, al;
    cvt8_hilo(xr[g&3][0], xr[g&3][1], ah, al);

    #pragma unroll
    for(int n=0;n<8;++n){
      acc[n] = __builtin_amdgcn_mfma_f32_16x16x32_bf16(ah, bf[n], acc[n], 0,0,0);
      acc[n] = __builtin_amdgcn_mfma_f32_16x16x32_bf16(al, bf[n], acc[n], 0,0,0);
    }

    if(g + 4 < NKS) ISSUE_X(g + 4);      // refill the slot just consumed

    if(ks == 6 && t < NST-1){            // stage boundary
      CVTW_M((t+1) & 1);                 // waits on mreg loads (compiler vmcnt)
      if(t < NST-2) ISSUE_M(t+2);
      __syncthreads();
    }
  }

  // epilogue — C/D layout: col=lane&15, row=(lane>>4)*4+j  [m89]
  if(EPI == 0){
    // PART layout [b][c][s][p]
    #pragma unroll
    for(int n=0;n<8;++n){
      int col  = n*16 + l15;
      int row0 = w*16 + hi4*4;
      #pragma unroll
      for(int j=0;j<4;++j)
        PART[(size_t)b*524288 + (size_t)(row0+j)*4096 + s*128 + col] = acc[n][j];
    }
  } else {
    float* o = OUT + (size_t)b * 16384;
    #pragma unroll
    for(int n=0;n<8;++n){
      int col  = n*16 + l15;
      int row0 = w*16 + hi4*4;
      #pragma unroll
      for(int j=0;j<4;++j) atomicAdd(&o[(size_t)(row0+j)*128 + col], acc[n][j]);
    }
  }
  #undef ISSUE_X
  #undef ISSUE_M
  #undef CVTW_M
}

// out[b][c][p] = sum_s PART[b][c][s][p] — fully coalesced reads.
__global__ void reduce_kernel(const float* __restrict__ PART, float* __restrict__ OUT){
  int bid = blockIdx.x;                          // 0..511
  int b   = bid >> 6;
  int c   = (bid & 63)*2 + (threadIdx.x >> 7);   // 0..127
  int p   = threadIdx.x & 127;
  size_t base_ = (size_t)b*524288 + (size_t)c*4096 + p;
  float sum = 0.f;
  #pragma unroll 8
  for(int k=0;k<32;++k) sum += PART[base_ + k*128];
  OUT[(size_t)b*16384 + c*128 + p] = sum;
}

__global__ void zero_kernel(float* __restrict__ OUT){
  int idx = blockIdx.x * 256 + threadIdx.x;
  if(idx < BATCH*CH*PN) OUT[idx] = 0.f;
}

extern "C" void kernel_launch(void* const* d_in, const int* in_sizes, int n_in,
                              void* d_out, int out_size, void* d_ws, size_t ws_size,
                              hipStream_t stream){
  const float* X  = (const float*)d_in[0];
  const float* Mk = (const float*)d_in[1];
  float* O = (float*)d_out;

  const size_t part_bytes = (size_t)BATCH * KSPLIT * CH * PN * sizeof(float); // 16.8 MB
  if(ws_size >= part_bytes && d_ws != nullptr){
    float* part = (float*)d_ws;
    raggr_kernel<0><<<dim3(BATCH*KSPLIT), dim3(512), 0, stream>>>(X, Mk, O, part);
    reduce_kernel<<<dim3(512), dim3(256), 0, stream>>>(part, O);
  } else {
    zero_kernel<<<dim3(512), dim3(256), 0, stream>>>(O);
    raggr_kernel<1><<<dim3(BATCH*KSPLIT), dim3(512), 0, stream>>>(X, Mk, O, nullptr);
  }
}